// Round 1
// baseline (21060.339 us; speedup 1.0000x reference)
//
#include <hip/hip_runtime.h>

// Bidirectional GRU, persistent-kernel design.
// B=32, T=1024, D=H=512. 64 workgroups = 2 directions x 32 gate-slices (16 h-cols each).
// Weights live in VGPRs as prebuilt MFMA B-fragments; h exchanged through LLC with
// agent-scope flags; h carried in fp32 registers per gate thread.

#define T_LEN 1024
#define B_SZ  32
#define D_SZ  512
#define H_SZ  512
#define NWG_DIR 32
#define JW 16
#define NTHR 768
#define KPAD 520   // padded LDS row (fp16 elems) to break bank conflicts

typedef __attribute__((ext_vector_type(8))) _Float16 half8;
typedef __attribute__((ext_vector_type(4))) _Float16 half4;
typedef __attribute__((ext_vector_type(4))) float f32x4;

__device__ __forceinline__ _Float16 f2h(float f) { return (_Float16)f; }

__global__ __launch_bounds__(NTHR, 1)
void gru2_persistent(const float* __restrict__ x,
                     const float* __restrict__ wih_fw, const float* __restrict__ whh_fw,
                     const float* __restrict__ bih_fw, const float* __restrict__ bhh_fw,
                     const float* __restrict__ wih_bw, const float* __restrict__ whh_bw,
                     const float* __restrict__ bih_bw, const float* __restrict__ bhh_bw,
                     float* __restrict__ out,
                     unsigned short* __restrict__ hex_u,
                     unsigned int* __restrict__ flags)
{
  __shared__ _Float16 S[B_SZ * KPAD];        // 33280 B: time-shared x_t / h staging
  __shared__ float Cp[24 * 16 * 17];          // 26112 B: 24 partial C tiles, +1 col pad
  __shared__ float biasLds[96];               // b_ih slice (48) + b_hh slice (48)

  _Float16* hex = reinterpret_cast<_Float16*>(hex_u);

  const int tid  = threadIdx.x;
  const int wgid = blockIdx.x;
  const int dir  = wgid >> 5;     // 0 = fw, 1 = bw
  const int g    = wgid & 31;     // gate slice: h-cols [g*16, g*16+16)
  const int wave = tid >> 6;
  const int lane = tid & 63;

  const float* wih = dir ? wih_bw : wih_fw;
  const float* whh = dir ? whh_bw : whh_fw;
  const float* bih = dir ? bih_bw : bih_fw;
  const float* bhh = dir ? bhh_bw : bhh_fw;

  if (tid < 48) {
    int grow = (tid >> 4) * H_SZ + g * JW + (tid & 15);
    biasLds[tid]      = bih[grow];
    biasLds[48 + tid] = bhh[grow];
  }

  // wave roles: 0-3 ih GEMM, 4-7 hh GEMM, 8-11 crew (x prefetch + flag poll)
  const bool isHh   = (wave >= 4 && wave < 8);
  const bool isCrew = (wave >= 8);
  const int  wv = isHh ? (wave - 4) : wave;  // 0..3 within gemm group
  const int  wm = wv & 1;                    // batch m-tile (16 rows each)
  const int  kh = wv >> 1;                   // K half: kk in [kh*8, kh*8+8)

  // ---- preload weight B-fragments into registers (persistent across all steps)
  // mfma_f32_16x16x32_f16 B-frag: lane l holds B[k][n] with n = l&15,
  // k = (l>>4)*8 + j (8 contiguous).  B[k][n] = W[row n][k]  (C = act · W^T).
  half8 Bf[3][8];
  if (!isCrew) {
    const float* W = isHh ? whh : wih;
    #pragma unroll
    for (int gam = 0; gam < 3; ++gam) {
      const int row = gam * H_SZ + g * JW + (lane & 15);
      #pragma unroll
      for (int i = 0; i < 8; ++i) {
        const int kk = kh * 8 + i;
        const float* src = W + (size_t)row * D_SZ + kk * 32 + ((lane >> 4) << 3);
        float4 v0 = *(const float4*)(src);
        float4 v1 = *(const float4*)(src + 4);
        half8 b;
        b[0]=f2h(v0.x); b[1]=f2h(v0.y); b[2]=f2h(v0.z); b[3]=f2h(v0.w);
        b[4]=f2h(v1.x); b[5]=f2h(v1.y); b[6]=f2h(v1.z); b[7]=f2h(v1.w);
        Bf[gam][i] = b;
      }
    }
  }

  // ---- prologue: stage x(t0) into S
  {
    const int t0 = dir ? (T_LEN - 1) : 0;
    for (int c = tid; c < B_SZ * D_SZ / 4; c += NTHR) {
      const int b = c >> 7, d = (c & 127) << 2;
      float4 v = *(const float4*)(x + ((size_t)b * T_LEN + t0) * D_SZ + d);
      half4 p; p[0]=f2h(v.x); p[1]=f2h(v.y); p[2]=f2h(v.z); p[3]=f2h(v.w);
      *(half4*)(S + b * KPAD + d) = p;
    }
  }
  __syncthreads();

  float hreg = 0.f;              // fp32 recurrent state, one h element per gate thread
  const int gb = tid >> 4;       // batch   (gate threads: tid < 512)
  const int gj = tid & 15;       // h-col within slice
  _Float16* hexd = hex + (size_t)dir * 2 * B_SZ * H_SZ;

  for (int s = 0; s < T_LEN; ++s) {
    const int t = dir ? (T_LEN - 1 - s) : s;
    const bool hasNext = (s + 1 < T_LEN);

    // ---- crew: issue x(t+1) loads early (latency hidden across phases A-C);
    //      wave 8 additionally polls the 32 producer flags for h(s-1).
    half4 xr[16];
    if (isCrew) {
      if (hasNext) {
        const int tn = dir ? (T_LEN - 2 - s) : (s + 1);
        const int ct = tid - 512;  // 0..255
        #pragma unroll
        for (int i = 0; i < 16; ++i) {
          const int c = ct + (i << 8);
          const int b = c >> 7, d = (c & 127) << 2;
          float4 v = *(const float4*)(x + ((size_t)b * T_LEN + tn) * D_SZ + d);
          half4 p; p[0]=f2h(v.x); p[1]=f2h(v.y); p[2]=f2h(v.z); p[3]=f2h(v.w);
          xr[i] = p;
        }
      }
      if (wave == 8 && s > 0) {
        unsigned int* fl = flags + ((size_t)dir * T_LEN + (s - 1)) * NWG_DIR;
        for (;;) {
          int v = (lane < NWG_DIR)
                    ? (int)__hip_atomic_load(&fl[lane], __ATOMIC_ACQUIRE,
                                             __HIP_MEMORY_SCOPE_AGENT)
                    : 1;
          if (__all(v != 0)) break;
          __builtin_amdgcn_s_sleep(2);
        }
      }
    }

    // ---- phase A: ih GEMM (waves 0-3) from S = x_t
    if (!isCrew && !isHh) {
      f32x4 acc[3] = {{0.f,0.f,0.f,0.f},{0.f,0.f,0.f,0.f},{0.f,0.f,0.f,0.f}};
      const int arow = wm * 16 + (lane & 15);
      const int koff = (lane >> 4) << 3;
      #pragma unroll
      for (int i = 0; i < 8; ++i) {
        const int kk = kh * 8 + i;
        half8 a = *(const half8*)(S + arow * KPAD + kk * 32 + koff);
        #pragma unroll
        for (int gam = 0; gam < 3; ++gam)
          acc[gam] = __builtin_amdgcn_mfma_f32_16x16x32_f16(a, Bf[gam][i], acc[gam], 0, 0, 0);
      }
      #pragma unroll
      for (int gam = 0; gam < 3; ++gam) {
        float* cp = Cp + (size_t)(((0*2 + kh)*3 + gam)*2 + wm) * 272
                       + (((lane >> 4) << 2)) * 17 + (lane & 15);
        #pragma unroll
        for (int vv = 0; vv < 4; ++vv) cp[vv * 17] = acc[gam][vv];
      }
    }
    __syncthreads();  // ih C-partials written; flags(s-1) confirmed (wave 8)

    // ---- phase B: stage h(s-1) fp16 into S (overwrites x_t; ih reads done)
    if (s > 0 && !isCrew) {
      __builtin_amdgcn_fence(__ATOMIC_ACQUIRE, "agent");  // see producers' stores (cross-XCD)
      const _Float16* hsrc = hexd + (size_t)((s - 1) & 1) * B_SZ * H_SZ;
      #pragma unroll
      for (int i = 0; i < 4; ++i) {
        const int c = tid + (i << 9);
        const int b = c >> 6, k = (c & 63) << 3;
        half8 hv = *(const half8*)(hsrc + (size_t)b * H_SZ + k);
        *(half8*)(S + b * KPAD + k) = hv;
      }
    }
    __syncthreads();  // S = h(s-1)

    // ---- phase C: hh GEMM (waves 4-7); at s==0 write zero partials
    if (isHh) {
      f32x4 acc[3] = {{0.f,0.f,0.f,0.f},{0.f,0.f,0.f,0.f},{0.f,0.f,0.f,0.f}};
      if (s > 0) {
        const int arow = wm * 16 + (lane & 15);
        const int koff = (lane >> 4) << 3;
        #pragma unroll
        for (int i = 0; i < 8; ++i) {
          const int kk = kh * 8 + i;
          half8 a = *(const half8*)(S + arow * KPAD + kk * 32 + koff);
          #pragma unroll
          for (int gam = 0; gam < 3; ++gam)
            acc[gam] = __builtin_amdgcn_mfma_f32_16x16x32_f16(a, Bf[gam][i], acc[gam], 0, 0, 0);
        }
      }
      #pragma unroll
      for (int gam = 0; gam < 3; ++gam) {
        float* cp = Cp + (size_t)(((1*2 + kh)*3 + gam)*2 + wm) * 272
                       + (((lane >> 4) << 2)) * 17 + (lane & 15);
        #pragma unroll
        for (int vv = 0; vv < 4; ++vv) cp[vv * 17] = acc[gam][vv];
      }
    }
    __syncthreads();  // hh C-partials written; S free

    // ---- phase D: gates (waves 0-7) || crew dumps x(t+1) into S
    if (isCrew) {
      if (hasNext) {
        const int ct = tid - 512;
        #pragma unroll
        for (int i = 0; i < 16; ++i) {
          const int c = ct + (i << 8);
          const int b = c >> 7, d = (c & 127) << 2;
          *(half4*)(S + b * KPAD + d) = xr[i];
        }
      }
    } else {
      const int mb = gb >> 4, rb = gb & 15;
      float sih[3], shh[3];
      #pragma unroll
      for (int gam = 0; gam < 3; ++gam) {
        float aih = 0.f, ahh = 0.f;
        #pragma unroll
        for (int q = 0; q < 2; ++q) {
          aih += Cp[(size_t)(((0*2+q)*3+gam)*2 + mb) * 272 + rb * 17 + gj];
          ahh += Cp[(size_t)(((1*2+q)*3+gam)*2 + mb) * 272 + rb * 17 + gj];
        }
        sih[gam] = aih + biasLds[gam * 16 + gj];
        shh[gam] = ahh + biasLds[48 + gam * 16 + gj];
      }
      const float r = 1.f / (1.f + __expf(-(sih[0] + shh[0])));
      const float z = 1.f / (1.f + __expf(-(sih[1] + shh[1])));
      const float n = tanhf(sih[2] + r * shh[2]);
      const float hn = (1.f - z) * n + z * hreg;
      hreg = hn;
      out[((size_t)gb * T_LEN + t) * (2 * H_SZ) + dir * H_SZ + g * JW + gj] = hn;
      hexd[(size_t)(s & 1) * B_SZ * H_SZ + (size_t)gb * H_SZ + g * JW + gj] = f2h(hn);
      if (s == T_LEN - 1) {
        float* hl = out + (size_t)B_SZ * T_LEN * (2 * H_SZ) + (size_t)dir * B_SZ * H_SZ;
        hl[gb * H_SZ + g * JW + gj] = hn;
      }
      __builtin_amdgcn_fence(__ATOMIC_RELEASE, "agent");  // push h/out to agent scope
    }
    __syncthreads();
    if (tid == 0)
      __hip_atomic_store(&flags[((size_t)dir * T_LEN + s) * NWG_DIR + g], 1u,
                         __ATOMIC_RELEASE, __HIP_MEMORY_SCOPE_AGENT);
  }
}

extern "C" void kernel_launch(void* const* d_in, const int* in_sizes, int n_in,
                              void* d_out, int out_size, void* d_ws, size_t ws_size,
                              hipStream_t stream) {
  const float* x      = (const float*)d_in[0];
  const float* wih_fw = (const float*)d_in[1];
  const float* whh_fw = (const float*)d_in[2];
  const float* bih_fw = (const float*)d_in[3];
  const float* bhh_fw = (const float*)d_in[4];
  const float* wih_bw = (const float*)d_in[5];
  const float* whh_bw = (const float*)d_in[6];
  const float* bih_bw = (const float*)d_in[7];
  const float* bhh_bw = (const float*)d_in[8];
  float* out = (float*)d_out;

  // workspace layout: flags [2][1024][32] u32 = 256 KB, then h exchange
  // [2 dir][2 parity][32][512] fp16 = 128 KB.  Total 384 KB.
  const size_t FLAGS_BYTES = (size_t)2 * T_LEN * NWG_DIR * sizeof(unsigned int);
  const size_t HEX_BYTES   = (size_t)2 * 2 * B_SZ * H_SZ * sizeof(unsigned short);
  if (ws_size < FLAGS_BYTES + HEX_BYTES) return;

  unsigned int*  flags = (unsigned int*)d_ws;
  unsigned short* hex  = (unsigned short*)((char*)d_ws + FLAGS_BYTES);

  hipMemsetAsync(flags, 0, FLAGS_BYTES, stream);
  gru2_persistent<<<dim3(64), dim3(NTHR), 0, stream>>>(
      x, wih_fw, whh_fw, bih_fw, bhh_fw, wih_bw, whh_bw, bih_bw, bhh_bw,
      out, hex, flags);
}

// Round 2
// 13232.162 us; speedup vs baseline: 1.5916x; 1.5916x over previous
//
#include <hip/hip_runtime.h>

// Bidirectional GRU, persistent-kernel design. Round 2.
// B=32, T=1024, D=H=512. 64 workgroups = 2 directions x 32 gate-slices (16 h-cols each).
// Weights live in VGPRs as prebuilt MFMA B-fragments.
// ROUND 2 CHANGE: all cross-WG communication (h exchange + flags) uses RELAXED
// agent-scope atomics (write-through to LLC, no buffer_inv/buffer_wbl2 L2
// tag-walks). Round 1's acquire/release fences cost ~2 L2 walks/step (~49k cy).
// Ordering: producer h-stores drained by __syncthreads' vmcnt(0) before flag
// store; consumer h-loads are LLC-point loads issued after flag confirmation.

#define T_LEN 1024
#define B_SZ  32
#define D_SZ  512
#define H_SZ  512
#define NWG_DIR 32
#define JW 16
#define NTHR 768
#define KPAD 520   // padded LDS row (fp16 elems) to break bank conflicts

typedef __attribute__((ext_vector_type(8))) _Float16 half8;
typedef __attribute__((ext_vector_type(4))) _Float16 half4;
typedef __attribute__((ext_vector_type(4))) float f32x4;

__device__ __forceinline__ _Float16 f2h(float f) { return (_Float16)f; }

__global__ __launch_bounds__(NTHR, 1)
void gru2_persistent(const float* __restrict__ x,
                     const float* __restrict__ wih_fw, const float* __restrict__ whh_fw,
                     const float* __restrict__ bih_fw, const float* __restrict__ bhh_fw,
                     const float* __restrict__ wih_bw, const float* __restrict__ whh_bw,
                     const float* __restrict__ bih_bw, const float* __restrict__ bhh_bw,
                     float* __restrict__ out,
                     unsigned int* __restrict__ hexu,
                     unsigned int* __restrict__ flags)
{
  __shared__ _Float16 S[B_SZ * KPAD];        // 33280 B: time-shared x_t / h staging
  __shared__ float Cp[24 * 16 * 17];          // 26112 B: 24 partial C tiles, +1 col pad
  __shared__ float biasLds[96];               // b_ih slice (48) + b_hh slice (48)

  const int tid  = threadIdx.x;
  const int wgid = blockIdx.x;
  const int dir  = wgid >> 5;     // 0 = fw, 1 = bw
  const int g    = wgid & 31;     // gate slice: h-cols [g*16, g*16+16)
  const int wave = tid >> 6;
  const int lane = tid & 63;

  const float* wih = dir ? wih_bw : wih_fw;
  const float* whh = dir ? whh_bw : whh_fw;
  const float* bih = dir ? bih_bw : bih_fw;
  const float* bhh = dir ? bhh_bw : bhh_fw;

  if (tid < 48) {
    int grow = (tid >> 4) * H_SZ + g * JW + (tid & 15);
    biasLds[tid]      = bih[grow];
    biasLds[48 + tid] = bhh[grow];
  }

  // wave roles: 0-3 ih GEMM, 4-7 hh GEMM, 8-11 crew (x prefetch + flag poll)
  const bool isHh   = (wave >= 4 && wave < 8);
  const bool isCrew = (wave >= 8);
  const int  wv = isHh ? (wave - 4) : wave;  // 0..3 within gemm group
  const int  wm = wv & 1;                    // batch m-tile (16 rows each)
  const int  kh = wv >> 1;                   // K half: kk in [kh*8, kh*8+8)

  // ---- preload weight B-fragments into registers (persistent across all steps)
  // mfma_f32_16x16x32_f16 B-frag: lane l holds B[k][n] with n = l&15,
  // k = (l>>4)*8 + j (8 contiguous).  B[k][n] = W[row n][k]  (C = act · W^T).
  half8 Bf[3][8];
  if (!isCrew) {
    const float* W = isHh ? whh : wih;
    #pragma unroll
    for (int gam = 0; gam < 3; ++gam) {
      const int row = gam * H_SZ + g * JW + (lane & 15);
      #pragma unroll
      for (int i = 0; i < 8; ++i) {
        const int kk = kh * 8 + i;
        const float* src = W + (size_t)row * D_SZ + kk * 32 + ((lane >> 4) << 3);
        float4 v0 = *(const float4*)(src);
        float4 v1 = *(const float4*)(src + 4);
        half8 b;
        b[0]=f2h(v0.x); b[1]=f2h(v0.y); b[2]=f2h(v0.z); b[3]=f2h(v0.w);
        b[4]=f2h(v1.x); b[5]=f2h(v1.y); b[6]=f2h(v1.z); b[7]=f2h(v1.w);
        Bf[gam][i] = b;
      }
    }
  }

  // ---- prologue: stage x(t0) into S
  {
    const int t0 = dir ? (T_LEN - 1) : 0;
    for (int c = tid; c < B_SZ * D_SZ / 4; c += NTHR) {
      const int b = c >> 7, d = (c & 127) << 2;
      float4 v = *(const float4*)(x + ((size_t)b * T_LEN + t0) * D_SZ + d);
      half4 p; p[0]=f2h(v.x); p[1]=f2h(v.y); p[2]=f2h(v.z); p[3]=f2h(v.w);
      *(half4*)(S + b * KPAD + d) = p;
    }
  }
  __syncthreads();

  float hreg = 0.f;              // fp32 recurrent state, one h element per gate thread
  const int gb = tid >> 4;       // batch   (gate threads: tid < 512)
  const int gj = tid & 15;       // h-col within slice

  for (int s = 0; s < T_LEN; ++s) {
    const int t = dir ? (T_LEN - 1 - s) : s;
    const bool hasNext = (s + 1 < T_LEN);

    // ---- crew: issue x(t+1) loads early (latency hidden across phases A-C);
    //      wave 8 additionally polls the 32 producer flags for h(s-1).
    half4 xr[16];
    if (isCrew) {
      if (hasNext) {
        const int tn = dir ? (T_LEN - 2 - s) : (s + 1);
        const int ct = tid - 512;  // 0..255
        #pragma unroll
        for (int i = 0; i < 16; ++i) {
          const int c = ct + (i << 8);
          const int b = c >> 7, d = (c & 127) << 2;
          float4 v = *(const float4*)(x + ((size_t)b * T_LEN + tn) * D_SZ + d);
          half4 p; p[0]=f2h(v.x); p[1]=f2h(v.y); p[2]=f2h(v.z); p[3]=f2h(v.w);
          xr[i] = p;
        }
      }
      if (wave == 8 && s > 0) {
        unsigned int* fl = flags + ((size_t)dir * T_LEN + (s - 1)) * NWG_DIR;
        for (;;) {
          // RELAXED poll: plain LLC-point load, no L2 invalidate per iteration.
          int v = (lane < NWG_DIR)
                    ? (int)__hip_atomic_load(&fl[lane], __ATOMIC_RELAXED,
                                             __HIP_MEMORY_SCOPE_AGENT)
                    : 1;
          if (__all(v != 0)) break;
          __builtin_amdgcn_s_sleep(1);
        }
      }
    }

    // ---- phase A: ih GEMM (waves 0-3) from S = x_t
    if (!isCrew && !isHh) {
      f32x4 acc[3] = {{0.f,0.f,0.f,0.f},{0.f,0.f,0.f,0.f},{0.f,0.f,0.f,0.f}};
      const int arow = wm * 16 + (lane & 15);
      const int koff = (lane >> 4) << 3;
      #pragma unroll
      for (int i = 0; i < 8; ++i) {
        const int kk = kh * 8 + i;
        half8 a = *(const half8*)(S + arow * KPAD + kk * 32 + koff);
        #pragma unroll
        for (int gam = 0; gam < 3; ++gam)
          acc[gam] = __builtin_amdgcn_mfma_f32_16x16x32_f16(a, Bf[gam][i], acc[gam], 0, 0, 0);
      }
      #pragma unroll
      for (int gam = 0; gam < 3; ++gam) {
        float* cp = Cp + (size_t)(((0*2 + kh)*3 + gam)*2 + wm) * 272
                       + (((lane >> 4) << 2)) * 17 + (lane & 15);
        #pragma unroll
        for (int vv = 0; vv < 4; ++vv) cp[vv * 17] = acc[gam][vv];
      }
    }
    __syncthreads();  // ih C-partials written; flags(s-1) confirmed (wave 8)

    // ---- phase B: stage h(s-1) fp16 into S (overwrites x_t; ih reads done).
    //      Relaxed agent atomic u32 loads: LLC-point reads, no fence needed —
    //      producer's stores reached LLC before its flag store (vmcnt order).
    if (s > 0 && !isCrew) {
      const unsigned int* hsrc =
          hexu + ((size_t)dir * 2 + ((s - 1) & 1)) * (B_SZ * H_SZ / 2);
      #pragma unroll
      for (int i = 0; i < 16; ++i) {
        const int c = tid + (i << 9);          // 512 threads x 16 = 8192 u32
        const int b = c >> 8, k2 = (c & 255) << 1;
        unsigned int v = __hip_atomic_load(&hsrc[c], __ATOMIC_RELAXED,
                                           __HIP_MEMORY_SCOPE_AGENT);
        *reinterpret_cast<unsigned int*>(&S[b * KPAD + k2]) = v;
      }
    }
    __syncthreads();  // S = h(s-1)

    // ---- phase C: hh GEMM (waves 4-7); at s==0 write zero partials
    if (isHh) {
      f32x4 acc[3] = {{0.f,0.f,0.f,0.f},{0.f,0.f,0.f,0.f},{0.f,0.f,0.f,0.f}};
      if (s > 0) {
        const int arow = wm * 16 + (lane & 15);
        const int koff = (lane >> 4) << 3;
        #pragma unroll
        for (int i = 0; i < 8; ++i) {
          const int kk = kh * 8 + i;
          half8 a = *(const half8*)(S + arow * KPAD + kk * 32 + koff);
          #pragma unroll
          for (int gam = 0; gam < 3; ++gam)
            acc[gam] = __builtin_amdgcn_mfma_f32_16x16x32_f16(a, Bf[gam][i], acc[gam], 0, 0, 0);
        }
      }
      #pragma unroll
      for (int gam = 0; gam < 3; ++gam) {
        float* cp = Cp + (size_t)(((1*2 + kh)*3 + gam)*2 + wm) * 272
                       + (((lane >> 4) << 2)) * 17 + (lane & 15);
        #pragma unroll
        for (int vv = 0; vv < 4; ++vv) cp[vv * 17] = acc[gam][vv];
      }
    }
    __syncthreads();  // hh C-partials written; S free

    // ---- phase D: gates (waves 0-7) || crew dumps x(t+1) into S
    if (isCrew) {
      if (hasNext) {
        const int ct = tid - 512;
        #pragma unroll
        for (int i = 0; i < 16; ++i) {
          const int c = ct + (i << 8);
          const int b = c >> 7, d = (c & 127) << 2;
          *(half4*)(S + b * KPAD + d) = xr[i];
        }
      }
    } else {
      const int mb = gb >> 4, rb = gb & 15;
      float sih[3], shh[3];
      #pragma unroll
      for (int gam = 0; gam < 3; ++gam) {
        float aih = 0.f, ahh = 0.f;
        #pragma unroll
        for (int q = 0; q < 2; ++q) {
          aih += Cp[(size_t)(((0*2+q)*3+gam)*2 + mb) * 272 + rb * 17 + gj];
          ahh += Cp[(size_t)(((1*2+q)*3+gam)*2 + mb) * 272 + rb * 17 + gj];
        }
        sih[gam] = aih + biasLds[gam * 16 + gj];
        shh[gam] = ahh + biasLds[48 + gam * 16 + gj];
      }
      const float r = 1.f / (1.f + __expf(-(sih[0] + shh[0])));
      const float z = 1.f / (1.f + __expf(-(sih[1] + shh[1])));
      const float n = tanhf(sih[2] + r * shh[2]);
      const float hn = (1.f - z) * n + z * hreg;
      hreg = hn;
      out[((size_t)gb * T_LEN + t) * (2 * H_SZ) + dir * H_SZ + g * JW + gj] = hn;

      // pack (even,odd) fp16 pair and write-through to LLC (relaxed agent atomic)
      const float hother = __shfl_xor(hn, 1);
      if ((gj & 1) == 0) {
        union { unsigned int u; _Float16 h[2]; } p;
        p.h[0] = f2h(hn); p.h[1] = f2h(hother);
        const size_t idx = ((size_t)dir * 2 + (s & 1)) * (B_SZ * H_SZ / 2)
                         + (size_t)gb * (H_SZ / 2) + (g * JW + gj) / 2;
        __hip_atomic_store(&hexu[idx], p.u, __ATOMIC_RELAXED,
                           __HIP_MEMORY_SCOPE_AGENT);
      }
      if (s == T_LEN - 1) {
        float* hl = out + (size_t)B_SZ * T_LEN * (2 * H_SZ) + (size_t)dir * B_SZ * H_SZ;
        hl[gb * H_SZ + g * JW + gj] = hn;
      }
    }
    // __syncthreads drains vmcnt(0) in every wave before the barrier, so all
    // h write-through stores have reached LLC before tid0 posts the flag.
    __syncthreads();
    if (tid == 0)
      __hip_atomic_store(&flags[((size_t)dir * T_LEN + s) * NWG_DIR + g], 1u,
                         __ATOMIC_RELAXED, __HIP_MEMORY_SCOPE_AGENT);
  }
}

extern "C" void kernel_launch(void* const* d_in, const int* in_sizes, int n_in,
                              void* d_out, int out_size, void* d_ws, size_t ws_size,
                              hipStream_t stream) {
  const float* x      = (const float*)d_in[0];
  const float* wih_fw = (const float*)d_in[1];
  const float* whh_fw = (const float*)d_in[2];
  const float* bih_fw = (const float*)d_in[3];
  const float* bhh_fw = (const float*)d_in[4];
  const float* wih_bw = (const float*)d_in[5];
  const float* whh_bw = (const float*)d_in[6];
  const float* bih_bw = (const float*)d_in[7];
  const float* bhh_bw = (const float*)d_in[8];
  float* out = (float*)d_out;

  // workspace layout: flags [2][1024][32] u32 = 256 KB, then h exchange
  // [2 dir][2 parity][32][256] u32 (packed fp16 pairs) = 128 KB. Total 384 KB.
  const size_t FLAGS_BYTES = (size_t)2 * T_LEN * NWG_DIR * sizeof(unsigned int);
  const size_t HEX_BYTES   = (size_t)2 * 2 * B_SZ * (H_SZ / 2) * sizeof(unsigned int);
  if (ws_size < FLAGS_BYTES + HEX_BYTES) return;

  unsigned int* flags = (unsigned int*)d_ws;
  unsigned int* hexu  = (unsigned int*)((char*)d_ws + FLAGS_BYTES);

  hipMemsetAsync(flags, 0, FLAGS_BYTES, stream);
  gru2_persistent<<<dim3(64), dim3(NTHR), 0, stream>>>(
      x, wih_fw, whh_fw, bih_fw, bhh_fw, wih_bw, whh_bw, bih_bw, bhh_bw,
      out, hexu, flags);
}

// Round 3
// 4482.578 us; speedup vs baseline: 4.6983x; 2.9519x over previous
//
#include <hip/hip_runtime.h>

// Bidirectional GRU, persistent-kernel. Round 3.
// B=32, T=1024, D=H=512. 64 WGs = 2 dirs x 32 gate-slices (16 h-cols each).
// ROUND 3 CHANGES vs r2:
//  - 512 threads / 8 waves; no crew waves, no LDS activation staging.
//  - ih waves (0-3): x fragments prefetched into REGISTERS (t+1 issued at top
//    of step, converted fp32->fp16 at use). x loads are plain cached loads.
//  - hh waves (4-7): poll flags themselves (overlapped with ih compute), then
//    load their 16x256 h-block straight into MFMA A-fragments with inline-asm
//    global_load_dwordx4 sc0 sc1 (pipelined, non-atomic; r2 used 16 scalar
//    ATOMIC dword loads/thread which serialized at ~900cy each).
//  - 2 barriers/step (Cp-ready, store-drain) instead of 4.
// Cross-WG protocol unchanged: relaxed agent-scope u32 atomics for h stores
// and flags; per-wave vmcnt(0) drain at the pre-flag barrier orders h stores
// before the flag; all cross-WG traffic bypasses L2 (sc0 sc1) so the LLC is
// the single coherence point. 2-parity h buffer; anti-overwrite is guaranteed
// by the flag chain (gen g+2 write requires all flags(g+1), posted after
// gen-g reads).

#define T_LEN 1024
#define B_SZ  32
#define D_SZ  512
#define H_SZ  512
#define NWG_DIR 32
#define JW 16
#define NTHR 512

typedef __attribute__((ext_vector_type(8))) _Float16 half8;
typedef __attribute__((ext_vector_type(4))) float f32x4;
typedef __attribute__((ext_vector_type(4))) int int4v;

__device__ __forceinline__ _Float16 f2h(float f) { return (_Float16)f; }

__global__ __launch_bounds__(NTHR, 2)
void gru2_persistent(const float* __restrict__ x,
                     const float* __restrict__ wih_fw, const float* __restrict__ whh_fw,
                     const float* __restrict__ bih_fw, const float* __restrict__ bhh_fw,
                     const float* __restrict__ wih_bw, const float* __restrict__ whh_bw,
                     const float* __restrict__ bih_bw, const float* __restrict__ bhh_bw,
                     float* __restrict__ out,
                     unsigned int* __restrict__ hexu,
                     unsigned int* __restrict__ flags)
{
  __shared__ float Cp[24 * 272];   // 24 C-partial tiles 16x16, row stride 17
  __shared__ float biasLds[96];    // b_ih slice (48) + b_hh slice (48)

  const int tid  = threadIdx.x;
  const int wgid = blockIdx.x;
  const int dir  = wgid >> 5;     // 0 = fw, 1 = bw
  const int g    = wgid & 31;     // gate slice: h-cols [g*16, g*16+16)
  const int wave = tid >> 6;
  const int lane = tid & 63;

  const float* wih = dir ? wih_bw : wih_fw;
  const float* whh = dir ? whh_bw : whh_fw;
  const float* bih = dir ? bih_bw : bih_fw;
  const float* bhh = dir ? bhh_bw : bhh_fw;

  if (tid < 48) {
    int grow = (tid >> 4) * H_SZ + g * JW + (tid & 15);
    biasLds[tid]      = bih[grow];
    biasLds[48 + tid] = bhh[grow];
  }

  const bool isHh = (wave >= 4);
  const int  wv = wave & 3;
  const int  wm = wv & 1;          // batch m-tile (16 rows)
  const int  kh = wv >> 1;         // K half: k in [kh*256, kh*256+256)

  // ---- weight B-fragments in registers, persistent across all steps.
  // mfma_f32_16x16x32_f16 B-frag: lane l holds B[k][n], n=l&15, k=(l>>4)*8+j.
  // B[k][n] = W[gam*H + slice_col n][k]  (C = act . W^T). Verified r1/r2.
  half8 Bf[3][8];
  {
    const float* W = isHh ? whh : wih;
    #pragma unroll
    for (int gam = 0; gam < 3; ++gam) {
      const int row = gam * H_SZ + g * JW + (lane & 15);
      #pragma unroll
      for (int i = 0; i < 8; ++i) {
        const float* src = W + (size_t)row * D_SZ + (kh * 8 + i) * 32 + ((lane >> 4) << 3);
        float4 v0 = *(const float4*)(src);
        float4 v1 = *(const float4*)(src + 4);
        half8 b;
        b[0]=f2h(v0.x); b[1]=f2h(v0.y); b[2]=f2h(v0.z); b[3]=f2h(v0.w);
        b[4]=f2h(v1.x); b[5]=f2h(v1.y); b[6]=f2h(v1.z); b[7]=f2h(v1.w);
        Bf[gam][i] = b;
      }
    }
  }

  // per-lane A-fragment geometry (batch row, k-offset)
  const int arow = wm * 16 + (lane & 15);          // batch row 0..31
  const int koff = (lane >> 4) << 3;               // 0,8,16,24

  // ---- ih prologue: load x(t0) fragment block into registers
  float4 xn[16];                                    // raw fp32, 2 float4 per k-subtile
  if (!isHh) {
    const int t0 = dir ? (T_LEN - 1) : 0;
    const float* base = x + ((size_t)arow * T_LEN + t0) * D_SZ + kh * 256 + koff;
    #pragma unroll
    for (int i = 0; i < 8; ++i) {
      xn[2*i]   = *(const float4*)(base + i * 32);
      xn[2*i+1] = *(const float4*)(base + i * 32 + 4);
    }
  }
  __syncthreads();

  float hreg = 0.f;               // fp32 recurrent state, one h element/thread
  const int gb = tid >> 4;        // batch row for gate phase (0..31)
  const int gj = tid & 15;        // h-col within slice

  for (int s = 0; s < T_LEN; ++s) {
    const int t = dir ? (T_LEN - 1 - s) : s;
    const bool hasNext = (s + 1 < T_LEN);

    f32x4 acc[3] = {{0.f,0.f,0.f,0.f},{0.f,0.f,0.f,0.f},{0.f,0.f,0.f,0.f}};

    if (!isHh) {
      // ---- convert prefetched x(t) to fp16 A-fragments
      half8 a[8];
      #pragma unroll
      for (int i = 0; i < 8; ++i) {
        float4 u = xn[2*i], w = xn[2*i+1];
        half8 h;
        h[0]=f2h(u.x); h[1]=f2h(u.y); h[2]=f2h(u.z); h[3]=f2h(u.w);
        h[4]=f2h(w.x); h[5]=f2h(w.y); h[6]=f2h(w.z); h[7]=f2h(w.w);
        a[i] = h;
      }
      // ---- issue x(t+1) prefetch (drains at B1, overlapped with hh path)
      if (hasNext) {
        const int tn = dir ? (T_LEN - 2 - s) : (s + 1);
        const float* base = x + ((size_t)arow * T_LEN + tn) * D_SZ + kh * 256 + koff;
        #pragma unroll
        for (int i = 0; i < 8; ++i) {
          xn[2*i]   = *(const float4*)(base + i * 32);
          xn[2*i+1] = *(const float4*)(base + i * 32 + 4);
        }
      }
      // ---- ih GEMM
      #pragma unroll
      for (int i = 0; i < 8; ++i)
        #pragma unroll
        for (int gam = 0; gam < 3; ++gam)
          acc[gam] = __builtin_amdgcn_mfma_f32_16x16x32_f16(a[i], Bf[gam][i], acc[gam], 0, 0, 0);
    } else {
      if (s > 0) {
        // ---- poll the 32 producer flags for h(s-1); overlaps ih compute
        const unsigned int* fl = flags + ((size_t)dir * T_LEN + (s - 1)) * NWG_DIR;
        for (;;) {
          unsigned int v = (lane < NWG_DIR)
              ? __hip_atomic_load(&fl[lane], __ATOMIC_RELAXED, __HIP_MEMORY_SCOPE_AGENT)
              : 1u;
          if (__all(v != 0)) break;
          __builtin_amdgcn_s_sleep(1);
        }
        // ---- load h(s-1) block straight into A-fragments (LLC-point, pipelined)
        const char* hb = (const char*)hexu
            + (((size_t)dir * 2 + ((s - 1) & 1)) * (B_SZ * (H_SZ / 2))) * 4;
        const char* p0 = hb + (size_t)arow * (H_SZ * 2) + (size_t)(kh * 256 + koff) * 2;
        int4v hv[8];
        #pragma unroll
        for (int i = 0; i < 8; ++i) {
          asm volatile("global_load_dwordx4 %0, %1, off sc0 sc1"
                       : "=&v"(hv[i]) : "v"(p0 + i * 64));
        }
        asm volatile("s_waitcnt vmcnt(0)" ::: "memory");
        __builtin_amdgcn_sched_barrier(0);
        // ---- hh GEMM
        #pragma unroll
        for (int i = 0; i < 8; ++i) {
          half8 a = __builtin_bit_cast(half8, hv[i]);
          #pragma unroll
          for (int gam = 0; gam < 3; ++gam)
            acc[gam] = __builtin_amdgcn_mfma_f32_16x16x32_f16(a, Bf[gam][i], acc[gam], 0, 0, 0);
        }
      }
      // s==0: acc stays zero (h0 = 0)
    }

    // ---- write C-partials: tile = ((src*2 + kh)*3 + gam)*2 + wm
    {
      const int src = isHh ? 1 : 0;
      #pragma unroll
      for (int gam = 0; gam < 3; ++gam) {
        float* cp = Cp + (size_t)(((src*2 + kh)*3 + gam)*2 + wm) * 272
                       + ((lane >> 4) << 2) * 17 + (lane & 15);
        #pragma unroll
        for (int vv = 0; vv < 4; ++vv) cp[vv * 17] = acc[gam][vv];
      }
    }
    __syncthreads();   // B1: Cp ready (also drains x-prefetch)

    // ---- gates: all 512 threads, one (b, gj) each
    {
      const int mb = gb >> 4, rb = gb & 15;
      float sih[3], shh[3];
      #pragma unroll
      for (int gam = 0; gam < 3; ++gam) {
        float aih = 0.f, ahh = 0.f;
        #pragma unroll
        for (int q = 0; q < 2; ++q) {
          aih += Cp[(size_t)(((0*2+q)*3+gam)*2 + mb) * 272 + rb * 17 + gj];
          ahh += Cp[(size_t)(((1*2+q)*3+gam)*2 + mb) * 272 + rb * 17 + gj];
        }
        sih[gam] = aih + biasLds[gam * 16 + gj];
        shh[gam] = ahh + biasLds[48 + gam * 16 + gj];
      }
      const float r = 1.f / (1.f + __expf(-(sih[0] + shh[0])));
      const float z = 1.f / (1.f + __expf(-(sih[1] + shh[1])));
      const float n = tanhf(sih[2] + r * shh[2]);
      const float hn = (1.f - z) * n + z * hreg;
      hreg = hn;
      out[((size_t)gb * T_LEN + t) * (2 * H_SZ) + dir * H_SZ + g * JW + gj] = hn;

      // pack (even,odd) fp16 pair, write-through to LLC
      const float hother = __shfl_xor(hn, 1);
      if ((gj & 1) == 0) {
        union { unsigned int u; _Float16 h[2]; } p;
        p.h[0] = f2h(hn); p.h[1] = f2h(hother);
        const size_t idx = ((size_t)dir * 2 + (s & 1)) * (B_SZ * (H_SZ / 2))
                         + (size_t)gb * (H_SZ / 2) + (g * JW + gj) / 2;
        __hip_atomic_store(&hexu[idx], p.u, __ATOMIC_RELAXED,
                           __HIP_MEMORY_SCOPE_AGENT);
      }
      if (s == T_LEN - 1) {
        float* hl = out + (size_t)B_SZ * T_LEN * (2 * H_SZ) + (size_t)dir * B_SZ * H_SZ;
        hl[gb * H_SZ + g * JW + gj] = hn;
      }
    }
    __syncthreads();   // B2: drains h/out stores (per-wave vmcnt(0) before s_barrier)
    if (tid == 0)
      __hip_atomic_store(&flags[((size_t)dir * T_LEN + s) * NWG_DIR + g], 1u,
                         __ATOMIC_RELAXED, __HIP_MEMORY_SCOPE_AGENT);
  }
}

extern "C" void kernel_launch(void* const* d_in, const int* in_sizes, int n_in,
                              void* d_out, int out_size, void* d_ws, size_t ws_size,
                              hipStream_t stream) {
  const float* x      = (const float*)d_in[0];
  const float* wih_fw = (const float*)d_in[1];
  const float* whh_fw = (const float*)d_in[2];
  const float* bih_fw = (const float*)d_in[3];
  const float* bhh_fw = (const float*)d_in[4];
  const float* wih_bw = (const float*)d_in[5];
  const float* whh_bw = (const float*)d_in[6];
  const float* bih_bw = (const float*)d_in[7];
  const float* bhh_bw = (const float*)d_in[8];
  float* out = (float*)d_out;

  // workspace: flags [2][1024][32] u32 = 256 KB; hexu [2 dir][2 parity][32][256] u32 = 128 KB
  const size_t FLAGS_BYTES = (size_t)2 * T_LEN * NWG_DIR * sizeof(unsigned int);
  const size_t HEX_BYTES   = (size_t)2 * 2 * B_SZ * (H_SZ / 2) * sizeof(unsigned int);
  if (ws_size < FLAGS_BYTES + HEX_BYTES) return;

  unsigned int* flags = (unsigned int*)d_ws;
  unsigned int* hexu  = (unsigned int*)((char*)d_ws + FLAGS_BYTES);

  hipMemsetAsync(flags, 0, FLAGS_BYTES, stream);
  gru2_persistent<<<dim3(64), dim3(NTHR), 0, stream>>>(
      x, wih_fw, whh_fw, bih_fw, bhh_fw, wih_bw, whh_bw, bih_bw, bhh_bw,
      out, hexu, flags);
}